// Round 5
// baseline (132.268 us; speedup 1.0000x reference)
//
#include <hip/hip_runtime.h>
#include <math.h>

#define B_TOTAL 2048
#define I_TOTAL 2048
#define O_TOTAL 2048
#define KW 64
#define NIN 6
#define BLOCK 256
#define TILE_B 16              // b-rows per main block (8 pairs)
#define NPAIR (TILE_B / 2)     // 8 pair-chunks, double-buffered
#define BBLOCKS (B_TOTAL / TILE_B)  /* 128 */
#define OBLOCKS (O_TOTAL / BLOCK)   /* 8   */
#define XPREP_BLOCKS (B_TOTAL / 2)  /* 1024 */

typedef __attribute__((ext_vector_type(2))) float f32x2;

static __device__ __forceinline__ f32x2 sp(float s) { f32x2 v; v.x = s; v.y = s; return v; }
static __device__ __forceinline__ f32x2 pfma(f32x2 a, f32x2 b, f32x2 c)
{ return __builtin_elementwise_fma(a, b, c); }

// ---------------------------------------------------------------------------
// prep_kernel: three jobs in one launch.
//  blocks [0,32):   table -> wT[k][o] via 64x65 LDS transpose (coalesced)
//     k<32 : sigmoid(table[o][k])                          ("lo")
//     k>=32: sigmoid(table[o][k]) - sigmoid(table[o][k-32]) (diff)
//  blocks [0,48):   mapping -> transposed int32 m32T[i][o]  (gid guard)
//  blocks [48,1072): x -> pair-interleaved xP[(b/2)*2048 + i][2]
//     so ONE ds_read_b64 in main gathers x for two b-rows at once.
// ---------------------------------------------------------------------------
__global__ __launch_bounds__(BLOCK) void prep_kernel(
    const float* __restrict__ x,
    const float* __restrict__ table,
    const unsigned int* __restrict__ map_raw,
    float* __restrict__ wT,
    int*   __restrict__ m32T,
    float* __restrict__ xP)
{
    const int t = threadIdx.x, bid = blockIdx.x;

    if (bid < 32) {
        __shared__ float sm[64][65];          // +1 pad: conflict-free col reads
        const int o0 = bid * 64;
        #pragma unroll
        for (int rep = 0; rep < 16; ++rep) {
            int idx = rep * 256 + t;          // 0..4095
            int ol = idx >> 6, k = idx & 63;
            float v = table[(o0 + ol) * KW + k];      // coalesced read
            sm[ol][k] = 1.0f / (1.0f + __expf(-v));
        }
        __syncthreads();
        #pragma unroll
        for (int rep = 0; rep < 16; ++rep) {
            int idx = rep * 256 + t;
            int k = idx >> 6, ol = idx & 63;
            float s = sm[ol][k];
            float v = (k >= 32) ? (s - sm[ol][k - 32]) : s;
            wT[k * O_TOTAL + o0 + ol] = v;            // coalesced write
        }
    } else if (bid >= 48) {
        // x pair-interleave: xP[(bp*2048 + i)*2 + q] = x[2*bp+q][i]
        const int bp = bid - 48;
        const float* r0 = x + (size_t)(2 * bp) * I_TOTAL;
        const float* r1 = r0 + I_TOTAL;
        f32x2* dst = (f32x2*)(xP + (size_t)bp * 2 * I_TOTAL);
        #pragma unroll
        for (int it = 0; it < I_TOTAL / BLOCK; ++it) {   // 8
            int i = it * BLOCK + t;
            f32x2 v; v.x = r0[i]; v.y = r1[i];           // two coalesced reads
            dst[i] = v;                                  // coalesced 8B store
        }
    }

    const int gid = bid * BLOCK + t;
    if (gid < O_TOTAL * NIN) {                // only blocks < 48 pass this
        // int64 little-endian with values < 2048 => odd u32 words are all 0.
        bool is64 = ((map_raw[1] | map_raw[3] | map_raw[5] | map_raw[7]) == 0u);
        int val = is64 ? (int)map_raw[2 * gid] : (int)map_raw[gid];
        int oo = gid / NIN, ii = gid - oo * NIN;
        m32T[ii * O_TOTAL + oo] = val;
    }
}

// ---------------------------------------------------------------------------
// Main, v5 = v2 structure (best so far) + halved issue counts:
//  * gathers: ds_read_b64 on pair-interleaved xP tile -> 6 gathers per TWO
//    rows (was 12). Same bytes, half the LDS instructions/latency slots.
//  * compute: whole multilinear tree in f32x2 -> v_pk_fma_f32 packed math,
//    ~47 VALU ops/row (was 94). Bitwise-identical fma per lane.
//  * everything else verbatim v2: async global_load_lds (pair-subtile is
//    contiguous in xP), double-buffer, one barrier per chunk, ww[64]
//    register-resident, coalesced out stores.
// ---------------------------------------------------------------------------
__device__ __forceinline__ void async_cp16(float* lds, const float* g)
{
    __builtin_amdgcn_global_load_lds(
        (const __attribute__((address_space(1))) void*)g,
        (__attribute__((address_space(3))) void*)lds,
        16, 0, 0);
}

__global__ __launch_bounds__(BLOCK, 3) void lut_main(
    const float* __restrict__ xP,
    const float* __restrict__ wT,
    const int*   __restrict__ m32T,
    float*       __restrict__ out)
{
    __shared__ float xs[2 * 2 * I_TOTAL];   // 2 bufs x 1 pair-subtile(16KB) = 32 KB

    const int o    = blockIdx.y * BLOCK + threadIdx.x;
    const int b0   = blockIdx.x * TILE_B;
    const int wave = threadIdx.x >> 6;
    const int lane = threadIdx.x & 63;

    // 64 weights (lo[0:32] + diff[32:64]) -> registers, coalesced loads
    float ww[KW];
    #pragma unroll
    for (int k = 0; k < KW; ++k) ww[k] = wT[k * O_TOTAL + o];

    int m[NIN];
    #pragma unroll
    for (int i = 0; i < NIN; ++i) m[i] = m32T[i * O_TOTAL + o];

    // pair-subtile p lives at xP + ((b0>>1)+p)*4096 floats (16 KB contiguous)
    const float* psrc = xP + (size_t)(b0 >> 1) * 2 * I_TOTAL;

    // --- prologue: stage pair 0 into buf 0 (16 instrs x 256 floats) -------
    #pragma unroll
    for (int ti = 0; ti < 4; ++ti) {
        int off = (wave * 4 + ti) * 256;             // wave-uniform float off
        async_cp16(&xs[off], psrc + off + lane * 4);
    }
    __syncthreads();   // drains own vmcnt(0), then barrier

    #pragma unroll 2
    for (int c = 0; c < NPAIR; ++c) {
        const int buf = c & 1;

        // issue DMA for next pair into the other buffer
        if (c + 1 < NPAIR) {
            const float* src = psrc + (size_t)(c + 1) * 2 * I_TOTAL;
            float* dst = &xs[(buf ^ 1) * 2 * I_TOTAL];
            #pragma unroll
            for (int ti = 0; ti < 4; ++ti) {
                int off = (wave * 4 + ti) * 256;
                async_cp16(dst + off, src + off + lane * 4);
            }
        }

        // --- gather both rows of the pair in one ds_read_b64 each ---------
        const int base = buf * 2 * I_TOTAL;          // compile-time via unroll 2
        f32x2 xv[NIN];
        #pragma unroll
        for (int i = 0; i < NIN; ++i)
            xv[i] = *(const f32x2*)(xs + base + 2 * m[i]);

        // --- packed multilinear tree (levels as before, f32x2 lanes=rows) -
        f32x2 tt[32];
        #pragma unroll
        for (int j = 0; j < 32; ++j) tt[j] = pfma(xv[5], sp(ww[j + 32]), sp(ww[j]));
        #pragma unroll
        for (int j = 0; j < 16; ++j) tt[j] = pfma(xv[4], tt[j + 16] - tt[j], tt[j]);
        #pragma unroll
        for (int j = 0; j < 8;  ++j) tt[j] = pfma(xv[3], tt[j + 8]  - tt[j], tt[j]);
        #pragma unroll
        for (int j = 0; j < 4;  ++j) tt[j] = pfma(xv[2], tt[j + 4]  - tt[j], tt[j]);
        #pragma unroll
        for (int j = 0; j < 2;  ++j) tt[j] = pfma(xv[1], tt[j + 2]  - tt[j], tt[j]);
        f32x2 res = pfma(xv[0], tt[1] - tt[0], tt[0]);

        out[(size_t)(b0 + 2 * c)     * O_TOTAL + o] = res.x;   // coalesced
        out[(size_t)(b0 + 2 * c + 1) * O_TOTAL + o] = res.y;   // coalesced

        __syncthreads();  // own DMA drained (vmcnt 0) + all waves done with buf
    }
}

extern "C" void kernel_launch(void* const* d_in, const int* in_sizes, int n_in,
                              void* d_out, int out_size, void* d_ws, size_t ws_size,
                              hipStream_t stream)
{
    const float*        x       = (const float*)d_in[0];
    const float*        table   = (const float*)d_in[1];
    const unsigned int* map_raw = (const unsigned int*)d_in[2];
    float* out  = (float*)d_out;

    float* wT   = (float*)d_ws;                                   // 512 KB
    int*   m32T = (int*)((char*)d_ws + (size_t)512 * 1024);       // 48 KB
    float* xP   = (float*)((char*)d_ws + (size_t)1024 * 1024);    // 16 MB

    prep_kernel<<<48 + XPREP_BLOCKS, BLOCK, 0, stream>>>(
        x, table, map_raw, wT, m32T, xP);

    dim3 grid(BBLOCKS, OBLOCKS);
    lut_main<<<grid, dim3(BLOCK), 0, stream>>>(xP, wT, m32T, out);
}

// Round 6
// 88.756 us; speedup vs baseline: 1.4902x; 1.4902x over previous
//
#include <hip/hip_runtime.h>
#include <math.h>

#define B_TOTAL 2048
#define I_TOTAL 2048
#define O_TOTAL 2048
#define KW 64
#define NIN 6
#define BLOCK 256
#define TILE_B 16              // b-rows per block (one tile = 128 KB of x)
#define CH 2                   // rows per LDS buffer (double-buffered)
#define NCHUNK (TILE_B / CH)   // 8
#define NTILES (B_TOTAL / TILE_B)   /* 128 */
#define OBLOCKS (O_TOTAL / BLOCK)   /* 8   */
#define MAIN_BLOCKS (NTILES * OBLOCKS)  /* 1024 */

// ---------------------------------------------------------------------------
// prep_kernel (verbatim from v2, which PASSED at 84.8):
//  blocks 0..31: table -> wT[k][o] via 64x65 LDS transpose (coalesced)
//     k<32 : sigmoid(table[o][k])                          ("lo")
//     k>=32: sigmoid(table[o][k]) - sigmoid(table[o][k-32]) (diff)
//  all 48 blocks: mapping -> transposed int32 m32T[i][o]
// ---------------------------------------------------------------------------
__global__ __launch_bounds__(BLOCK) void prep_kernel(
    const float* __restrict__ table,
    const unsigned int* __restrict__ map_raw,
    float* __restrict__ wT,
    int* __restrict__ m32T)
{
    const int t = threadIdx.x;

    if (blockIdx.x < 32) {
        __shared__ float sm[64][65];          // +1 pad: conflict-free col reads
        const int o0 = blockIdx.x * 64;
        #pragma unroll
        for (int rep = 0; rep < 16; ++rep) {
            int idx = rep * 256 + t;          // 0..4095
            int ol = idx >> 6, k = idx & 63;
            float v = table[(o0 + ol) * KW + k];      // coalesced read
            sm[ol][k] = 1.0f / (1.0f + __expf(-v));
        }
        __syncthreads();
        #pragma unroll
        for (int rep = 0; rep < 16; ++rep) {
            int idx = rep * 256 + t;
            int k = idx >> 6, ol = idx & 63;
            float s = sm[ol][k];
            float v = (k >= 32) ? (s - sm[ol][k - 32]) : s;
            wT[k * O_TOTAL + o0 + ol] = v;            // coalesced write
        }
    }

    const int gid = blockIdx.x * BLOCK + t;           // 48*256 = 12288 exactly
    if (gid < O_TOTAL * NIN) {
        // int64 little-endian with values < 2048 => odd u32 words are all 0.
        bool is64 = ((map_raw[1] | map_raw[3] | map_raw[5] | map_raw[7]) == 0u);
        int val = is64 ? (int)map_raw[2 * gid] : (int)map_raw[gid];
        int oo = gid / NIN, ii = gid - oo * NIN;
        m32T[ii * O_TOTAL + oo] = val;
    }
}

// ---------------------------------------------------------------------------
// Main, v6 = v2 (best: 84.8us) + ONE change: XCD-temporal swizzle.
//   v5 counters showed FETCH=49MB (~3x the 16.8MB x footprint) and 20%-HBM
//   latency-bound execution: the 8 o-blocks sharing a b-tile were 128 apart
//   in linear id -> same XCD but temporally separated -> tile evicted from
//   the 4MiB L2 before re-readers arrived -> HBM restage at ~900cy latency
//   that the ~500cy/chunk compute can't cover.
//   New mapping (round-robin XCD = bid&7 assumed, perf-only):
//     c    = bid & 7;          // XCD
//     q    = bid >> 3;         // position in this XCD's issue stream
//     ob   = q & 7;            // FAST: o-block     (8 consumers of a tile
//     tloc = q >> 3;           //                    are temporally adjacent)
//     tile = c * 16 + tloc;    // SLOW: b-tile, owned by exactly one XCD
//   => x fetched from HBM once device-wide; dbuf restages become ~250cy L2
//   hits, which the per-chunk compute fully covers.
//   Everything else verbatim v2: scalar fma tree (bit-identical results),
//   ww[64] register-resident, async global_load_lds double-buffer.
// ---------------------------------------------------------------------------
__device__ __forceinline__ void async_cp16(float* lds, const float* g)
{
    __builtin_amdgcn_global_load_lds(
        (const __attribute__((address_space(1))) void*)g,
        (__attribute__((address_space(3))) void*)lds,
        16, 0, 0);
}

__global__ __launch_bounds__(BLOCK, 3) void lut_main(
    const float* __restrict__ x,
    const float* __restrict__ wT,
    const int*   __restrict__ m32T,
    float*       __restrict__ out)
{
    __shared__ float xs[2 * CH * I_TOTAL];   // 2 bufs x 2 rows x 8KB = 32 KB

    const int bid  = blockIdx.x;
    const int c    = bid & 7;                // XCD (round-robin assumption)
    const int q    = bid >> 3;
    const int ob   = q & 7;                  // fast: o-block within XCD
    const int tloc = q >> 3;                 // slow: tile within XCD
    const int tile = c * (NTILES / 8) + tloc;

    const int o    = ob * BLOCK + threadIdx.x;
    const int b0   = tile * TILE_B;
    const int wave = threadIdx.x >> 6;
    const int lane = threadIdx.x & 63;

    // 64 weights (lo[0:32] + diff[32:64]) -> registers, coalesced loads
    float ww[KW];
    #pragma unroll
    for (int k = 0; k < KW; ++k) ww[k] = wT[k * O_TOTAL + o];

    int m[NIN];
    #pragma unroll
    for (int i = 0; i < NIN; ++i) m[i] = m32T[i * O_TOTAL + o];

    // --- prologue: stage chunk 0 into buf 0 -------------------------------
    {
        const float* src = x + (size_t)b0 * I_TOTAL;
        #pragma unroll
        for (int ti = 0; ti < 4; ++ti) {
            int off = (wave * 4 + ti) * 256;         // wave-uniform float off
            async_cp16(&xs[off], src + off + lane * 4);
        }
    }
    __syncthreads();   // drains own vmcnt(0), then barrier

    #pragma unroll 2
    for (int cc = 0; cc < NCHUNK; ++cc) {
        const int buf = cc & 1;

        // issue DMA for next chunk into the other buffer (L2-hit latency,
        // covered by this chunk's compute; drained by trailing syncthreads)
        if (cc + 1 < NCHUNK) {
            const float* src = x + (size_t)(b0 + (cc + 1) * CH) * I_TOTAL;
            float* dst = &xs[(buf ^ 1) * CH * I_TOTAL];
            #pragma unroll
            for (int ti = 0; ti < 4; ++ti) {
                int off = (wave * 4 + ti) * 256;
                async_cp16(dst + off, src + off + lane * 4);
            }
        }

        #pragma unroll
        for (int cr = 0; cr < CH; ++cr) {
            const int rowc = (buf * CH + cr) * I_TOTAL;   // compile-time
            float xv[NIN];
            #pragma unroll
            for (int i = 0; i < NIN; ++i) xv[i] = xs[rowc + m[i]];  // LDS gather

            // multilinear contraction; level 0 uses precomputed lo/diff
            float tt[32];
            #pragma unroll
            for (int j = 0; j < 32; ++j) tt[j] = fmaf(xv[5], ww[j + 32], ww[j]);
            #pragma unroll
            for (int j = 0; j < 16; ++j) tt[j] = fmaf(xv[4], tt[j + 16] - tt[j], tt[j]);
            #pragma unroll
            for (int j = 0; j < 8;  ++j) tt[j] = fmaf(xv[3], tt[j + 8]  - tt[j], tt[j]);
            #pragma unroll
            for (int j = 0; j < 4;  ++j) tt[j] = fmaf(xv[2], tt[j + 4]  - tt[j], tt[j]);
            #pragma unroll
            for (int j = 0; j < 2;  ++j) tt[j] = fmaf(xv[1], tt[j + 2]  - tt[j], tt[j]);
            float res = fmaf(xv[0], tt[1] - tt[0], tt[0]);

            out[(size_t)(b0 + cc * CH + cr) * O_TOTAL + o] = res;  // coalesced
        }

        __syncthreads();  // own DMA drained (vmcnt 0) + all waves done with buf
    }
}

extern "C" void kernel_launch(void* const* d_in, const int* in_sizes, int n_in,
                              void* d_out, int out_size, void* d_ws, size_t ws_size,
                              hipStream_t stream)
{
    const float*        x       = (const float*)d_in[0];
    const float*        table   = (const float*)d_in[1];
    const unsigned int* map_raw = (const unsigned int*)d_in[2];
    float* out  = (float*)d_out;
    float* wT   = (float*)d_ws;                                        // 512 KB
    int*   m32T = (int*)((char*)d_ws + (size_t)O_TOTAL * KW * sizeof(float)); // +48 KB

    prep_kernel<<<48, BLOCK, 0, stream>>>(table, map_raw, wT, m32T);

    lut_main<<<MAIN_BLOCKS, dim3(BLOCK), 0, stream>>>(x, wT, m32T, out);
}